// Round 1
// baseline (305.128 us; speedup 1.0000x reference)
//
#include <hip/hip_runtime.h>

// Problem: L=200 events consumed in pairs -> S=100 scan steps over u[N,N,3],
// N=256. Each (n,m) cell is an independent 100-step chain; the per-node
// dot/exp factors f[t][n] are state-independent and precomputed per block.
//
// Layout facts:
//   event_list [201,256,256]  (use first 200 rows)
//   a          [200,256,256,3]
//   w          [200,256,1,256]
//   u_begin    [256,256,3]
//   liner_w    [256,3], liner_b [256]
//   out        [100,256,256]  float32

#define NN   256
#define TT   200
#define SS   100

__global__ __launch_bounds__(256) void fused_scan_kernel(
    const float* __restrict__ timep,   // [2]
    const float* __restrict__ ev,      // [201,N,N]
    const float* __restrict__ ub,      // [N,N,3]
    const float* __restrict__ a,       // [T,N,N,3]
    const float* __restrict__ w,       // [T,N,1,N]
    const float* __restrict__ lw,      // [N,3]
    const float* __restrict__ lb,      // [N]
    float* __restrict__ out)           // [S,N,N]
{
    __shared__ float fs[TT];

    const int n    = blockIdx.x;
    const int m    = threadIdx.x;
    const int lane = m & 63;
    const int wid  = m >> 6;

    const float t0 = timep[0];
    const float t1 = timep[1];
    // wave `wid` handles t = wid, wid+4, ... -> parity of t is wid&1 (uniform)
    const float tsel = (wid & 1) ? t1 : t0;

    // ---- prologue: f[t] = exp(-dot(w[t,n,0,:], ev[t,n,:]) * time[t&1]) ----
    // 4 waves, each does 50 t's, 2 per iteration (t, t+4) for load MLP.
    {
        const size_t rowoff = (size_t)n * NN;
        for (int t = wid; t < TT; t += 8) {
            const int t2 = t + 4;  // t+4 <= 199 always (max t here is 195)
            const float4* wp0 = (const float4*)(w  + (size_t)t  * (NN * NN) + rowoff);
            const float4* ep0 = (const float4*)(ev + (size_t)t  * (NN * NN) + rowoff);
            const float4* wp1 = (const float4*)(w  + (size_t)t2 * (NN * NN) + rowoff);
            const float4* ep1 = (const float4*)(ev + (size_t)t2 * (NN * NN) + rowoff);
            float4 wv0 = wp0[lane];
            float4 ev0 = ep0[lane];
            float4 wv1 = wp1[lane];
            float4 ev1 = ep1[lane];
            float d0 = wv0.x * ev0.x;
            d0 = fmaf(wv0.y, ev0.y, d0);
            d0 = fmaf(wv0.z, ev0.z, d0);
            d0 = fmaf(wv0.w, ev0.w, d0);
            float d1 = wv1.x * ev1.x;
            d1 = fmaf(wv1.y, ev1.y, d1);
            d1 = fmaf(wv1.z, ev1.z, d1);
            d1 = fmaf(wv1.w, ev1.w, d1);
#pragma unroll
            for (int off = 1; off < 64; off <<= 1) {
                d0 += __shfl_xor(d0, off, 64);
                d1 += __shfl_xor(d1, off, 64);
            }
            if (lane == 0) {
                fs[t]  = __expf(-d0 * tsel);
                fs[t2] = __expf(-d1 * tsel);
            }
        }
    }
    __syncthreads();

    // ---- main scan: one thread per (n,m) chain ----
    const size_t base    = (size_t)n * (NN * 3) + (size_t)m * 3;  // offset inside one t-slab
    const size_t TSTRIDE = (size_t)NN * NN * 3;                   // 196608 floats per t
    const float* ap = a + base;

    float u0 = ub[base + 0];
    float u1 = ub[base + 1];
    float u2 = ub[base + 2];

    const float w0 = lw[n * 3 + 0];
    const float w1 = lw[n * 3 + 1];
    const float w2 = lw[n * 3 + 2];
    const float bb = lb[n];

    // prefetch depth 2: cur = step s, nxt = step s+1
    float c0x = ap[0],            c0y = ap[1],            c0z = ap[2];
    float c1x = ap[TSTRIDE + 0],  c1y = ap[TSTRIDE + 1],  c1z = ap[TSTRIDE + 2];
    const float* ap1 = ap + 2 * TSTRIDE;
    float n0x = ap1[0],           n0y = ap1[1],           n0z = ap1[2];
    float n1x = ap1[TSTRIDE + 0], n1y = ap1[TSTRIDE + 1], n1z = ap1[TSTRIDE + 2];

    float* op = out + (size_t)n * NN + m;

    for (int s = 0; s < SS; ++s) {
        // issue prefetch for step s+2 (clamped; redundant re-read of t=0,1 at tail)
        const int sp = (s + 2 < SS) ? (s + 2) : 0;
        const float* app = ap + (size_t)(2 * sp) * TSTRIDE;
        float p0x = app[0];
        float p0y = app[1];
        float p0z = app[2];
        float p1x = app[TSTRIDE + 0];
        float p1y = app[TSTRIDE + 1];
        float p1z = app[TSTRIDE + 2];

        const float f0 = fs[2 * s];
        const float f1 = fs[2 * s + 1];

        float l0 = fmaf(c0x, f0, fmaf(c1x, f1, u0));
        float l1 = fmaf(c0y, f0, fmaf(c1y, f1, u1));
        float l2 = fmaf(c0z, f0, fmaf(c1z, f1, u2));
        float mx = fmaxf(l0, fmaxf(l1, l2));
        float e0 = __expf(l0 - mx);
        float e1 = __expf(l1 - mx);
        float e2 = __expf(l2 - mx);
        float inv = __builtin_amdgcn_rcpf(e0 + e1 + e2);
        u0 = e0 * inv;
        u1 = e1 * inv;
        u2 = e2 * inv;
        op[(size_t)s * (NN * NN)] = fmaf(u0, w0, fmaf(u1, w1, fmaf(u2, w2, bb)));

        // rotate prefetch registers
        c0x = n0x; c0y = n0y; c0z = n0z;
        c1x = n1x; c1y = n1y; c1z = n1z;
        n0x = p0x; n0y = p0y; n0z = p0z;
        n1x = p1x; n1y = p1y; n1z = p1z;
    }
}

extern "C" void kernel_launch(void* const* d_in, const int* in_sizes, int n_in,
                              void* d_out, int out_size, void* d_ws, size_t ws_size,
                              hipStream_t stream) {
    const float* timep = (const float*)d_in[0];
    const float* ev    = (const float*)d_in[1];
    const float* ub    = (const float*)d_in[2];
    const float* a     = (const float*)d_in[3];
    const float* w     = (const float*)d_in[4];
    const float* lw    = (const float*)d_in[5];
    const float* lb    = (const float*)d_in[6];
    float* out = (float*)d_out;

    fused_scan_kernel<<<NN, 256, 0, stream>>>(timep, ev, ub, a, w, lw, lb, out);
}